// Round 1
// baseline (196.943 us; speedup 1.0000x reference)
//
#include <hip/hip_runtime.h>
#include <hip/hip_bf16.h>

#define D_  2048
#define IN_ 512
#define T_  4096
#define G4_ 8192

typedef __attribute__((ext_vector_type(4))) float f32x4;
typedef __attribute__((ext_vector_type(8))) short s16x8;

// ws layout (float offsets) — all multiples of 512 region starts, 16B aligned
#define WS_PROD    0                       // T_
#define WS_Q       (T_)                    // D_
#define WS_X       (T_ + D_)               // D_+IN_ : [context | data]
#define WS_PARTIAL (WS_X + D_ + IN_)       // T_*32
#define WS_SCORE   (WS_PARTIAL + T_*32)    // T_
#define WS_ATTN    (WS_SCORE + T_)         // T_
#define WS_GATES   (WS_ATTN + T_)          // G4_
#define WS_FC      (WS_GATES + G4_)        // D_
#define WS_L1      (WS_FC + D_)            // D_
#define WS_HN      (WS_L1 + D_)            // D_

__device__ inline short bfbits(__hip_bfloat16 h) {
  union { __hip_bfloat16 b; short s; } u; u.b = h; return u.s;
}

// full-row dot by one wave; returns sum in all lanes
__device__ inline float wave_dot4(const float* __restrict__ w,
                                  const float* __restrict__ x, int n4, int lane) {
  float s = 0.f;
  const f32x4* w4 = (const f32x4*)w;
  const f32x4* x4 = (const f32x4*)x;
  for (int c = lane; c < n4; c += 64) {
    f32x4 a = w4[c], b = x4[c];
    s += a[0]*b[0] + a[1]*b[1] + a[2]*b[2] + a[3]*b[3];
  }
  #pragma unroll
  for (int m = 32; m >= 1; m >>= 1) s += __shfl_xor(s, m, 64);
  return s;
}

// ---- kernel 1: prod[t], q = W_w @ h0, copy data into x tail ----
__global__ __launch_bounds__(256) void k_prep(const float* __restrict__ Ww,
    const float* __restrict__ h0, const float* __restrict__ pi,
    const float* __restrict__ data, const int* __restrict__ ip,
    float* __restrict__ ws) {
  const int tid = threadIdx.x, bid = blockIdx.x;
  const int gidx = bid * 256 + tid;
  const int op = ip[0] + 1;
  if (gidx < T_) {
    float p = 0.f;
    if (gidx >= op - 1) {
      int idx = op + T_ - gidx - 2;
      idx = idx < 0 ? 0 : (idx > T_ - 1 ? T_ - 1 : idx);
      p = pi[idx];
    }
    ws[WS_PROD + gidx] = p;
  }
  if (gidx < IN_) ws[WS_X + D_ + gidx] = data[gidx];
  const int wid = tid >> 6, lane = tid & 63;
  const int row = bid * 4 + wid;
  if (row < D_) {
    float s = wave_dot4(Ww + (size_t)row * D_, h0, D_ / 4, lane);
    if (lane == 0) ws[WS_Q + row] = s;
  }
}

// ---- kernel 2: fused split-bf16 MFMA GEMM + tanh/V epilogue -> partial ----
__global__ __launch_bounds__(256) void k_gemm_score(
    const float* __restrict__ enc, const float* __restrict__ Uw,
    const float* __restrict__ Vw, float* __restrict__ ws) {
  __shared__ __align__(16) short Ahi[128 * 40];
  __shared__ __align__(16) short Alo[128 * 40];
  __shared__ __align__(16) short Bhi[128 * 40];
  __shared__ __align__(16) short Blo[128 * 40];
  const int tid = threadIdx.x;
  const int lane = tid & 63, wid = tid >> 6;
  const int wr = wid >> 1, wc = wid & 1;
  const int g = lane >> 4, lr = lane & 15;
  const int mb = blockIdx.x, nb = blockIdx.y;

  f32x4 acc[4][4];
  #pragma unroll
  for (int m = 0; m < 4; ++m)
    #pragma unroll
    for (int n = 0; n < 4; ++n) acc[m][n] = (f32x4){0.f, 0.f, 0.f, 0.f};

  const int srow = tid >> 1;
  const int soff = (tid & 1) * 16;
  const float* pa0 = enc + (size_t)(mb * 128 + srow) * D_ + soff;
  const float* pb0 = Uw  + (size_t)(nb * 128 + srow) * D_ + soff;
  const int sbase = srow * 40 + soff;

  for (int ks = 0; ks < D_ / 32; ++ks) {
    __align__(16) float av[16], bv[16];
    #pragma unroll
    for (int v = 0; v < 4; ++v) {
      *(f32x4*)&av[v * 4] = *(const f32x4*)(pa0 + ks * 32 + v * 4);
      *(f32x4*)&bv[v * 4] = *(const f32x4*)(pb0 + ks * 32 + v * 4);
    }
    __syncthreads();   // previous iteration's reads done before overwrite
    __align__(16) short ah[16], al[16], bh[16], bl[16];
    #pragma unroll
    for (int e = 0; e < 16; ++e) {
      __hip_bfloat16 h = __float2bfloat16(av[e]);
      __hip_bfloat16 l = __float2bfloat16(av[e] - __bfloat162float(h));
      ah[e] = bfbits(h); al[e] = bfbits(l);
      h = __float2bfloat16(bv[e]);
      l = __float2bfloat16(bv[e] - __bfloat162float(h));
      bh[e] = bfbits(h); bl[e] = bfbits(l);
    }
    *(s16x8*)&Ahi[sbase]     = *(s16x8*)&ah[0];
    *(s16x8*)&Ahi[sbase + 8] = *(s16x8*)&ah[8];
    *(s16x8*)&Alo[sbase]     = *(s16x8*)&al[0];
    *(s16x8*)&Alo[sbase + 8] = *(s16x8*)&al[8];
    *(s16x8*)&Bhi[sbase]     = *(s16x8*)&bh[0];
    *(s16x8*)&Bhi[sbase + 8] = *(s16x8*)&bh[8];
    *(s16x8*)&Blo[sbase]     = *(s16x8*)&bl[0];
    *(s16x8*)&Blo[sbase + 8] = *(s16x8*)&bl[8];
    __syncthreads();

    s16x8 afh[4], afl[4], bfh[4], bfl[4];
    #pragma unroll
    for (int m = 0; m < 4; ++m) {
      const int r = wr * 64 + m * 16 + lr;
      afh[m] = *(const s16x8*)&Ahi[r * 40 + g * 8];
      afl[m] = *(const s16x8*)&Alo[r * 40 + g * 8];
    }
    #pragma unroll
    for (int n = 0; n < 4; ++n) {
      const int r = wc * 64 + n * 16 + lr;
      bfh[n] = *(const s16x8*)&Bhi[r * 40 + g * 8];
      bfl[n] = *(const s16x8*)&Blo[r * 40 + g * 8];
    }
    #pragma unroll
    for (int m = 0; m < 4; ++m)
      #pragma unroll
      for (int n = 0; n < 4; ++n) {
        acc[m][n] = __builtin_amdgcn_mfma_f32_16x16x32_bf16(afh[m], bfh[n], acc[m][n], 0, 0, 0);
        acc[m][n] = __builtin_amdgcn_mfma_f32_16x16x32_bf16(afh[m], bfl[n], acc[m][n], 0, 0, 0);
        acc[m][n] = __builtin_amdgcn_mfma_f32_16x16x32_bf16(afl[m], bfh[n], acc[m][n], 0, 0, 0);
      }
  }

  // epilogue: score partial = sum_d V[d]*tanh(q[d] + prod[t]*C[t][d])
  const float* q    = ws + WS_Q;
  const float* prod = ws + WS_PROD;
  float* partial    = ws + WS_PARTIAL;
  float Vv[4], qv[4];
  #pragma unroll
  for (int n = 0; n < 4; ++n) {
    const int d = nb * 128 + wc * 64 + n * 16 + lr;
    Vv[n] = Vw[d]; qv[n] = q[d];
  }
  #pragma unroll
  for (int m = 0; m < 4; ++m) {
    const int tb = mb * 128 + wr * 64 + m * 16 + g * 4;
    #pragma unroll
    for (int r = 0; r < 4; ++r) {
      const int t = tb + r;
      const float p = prod[t];
      float s = 0.f;
      #pragma unroll
      for (int n = 0; n < 4; ++n) s += Vv[n] * tanhf(qv[n] + p * acc[m][n][r]);
      s += __shfl_xor(s, 1, 64);
      s += __shfl_xor(s, 2, 64);
      s += __shfl_xor(s, 4, 64);
      s += __shfl_xor(s, 8, 64);
      if (lr == 0) partial[(size_t)t * 32 + nb * 2 + wc] = s;
    }
  }
}

// ---- kernel 3: reduce partials -> masked score ----
__global__ __launch_bounds__(256) void k_score(const int* __restrict__ ip,
                                               float* __restrict__ ws) {
  const int t = blockIdx.x * 256 + threadIdx.x;
  const int op = ip[0] + 1;
  const float* p = ws + WS_PARTIAL + (size_t)t * 32;
  float s = 0.f;
  #pragma unroll
  for (int c = 0; c < 32; ++c) s += p[c];
  ws[WS_SCORE + t] = (t < op) ? 0.f : s;
}

// ---- kernel 4: softmax over T scores (single block) ----
__global__ __launch_bounds__(1024) void k_attn(float* __restrict__ ws) {
  __shared__ float sm[16];
  const int tid = threadIdx.x, lane = tid & 63, wid = tid >> 6;
  float v[4];
  #pragma unroll
  for (int j = 0; j < 4; ++j) v[j] = ws[WS_SCORE + tid + j * 1024];
  float mx = fmaxf(fmaxf(v[0], v[1]), fmaxf(v[2], v[3]));
  #pragma unroll
  for (int m = 32; m >= 1; m >>= 1) mx = fmaxf(mx, __shfl_xor(mx, m, 64));
  if (lane == 0) sm[wid] = mx;
  __syncthreads();
  if (tid == 0) {
    float m2 = sm[0];
    for (int w = 1; w < 16; ++w) m2 = fmaxf(m2, sm[w]);
    sm[0] = m2;
  }
  __syncthreads();
  mx = sm[0];
  __syncthreads();
  float e[4], ls = 0.f;
  #pragma unroll
  for (int j = 0; j < 4; ++j) { e[j] = expf(v[j] - mx); ls += e[j]; }
  #pragma unroll
  for (int m = 32; m >= 1; m >>= 1) ls += __shfl_xor(ls, m, 64);
  if (lane == 0) sm[wid] = ls;
  __syncthreads();
  if (tid == 0) {
    float s2 = 0.f;
    for (int w = 0; w < 16; ++w) s2 += sm[w];
    sm[0] = s2;
  }
  __syncthreads();
  const float inv = 1.f / sm[0];
  #pragma unroll
  for (int j = 0; j < 4; ++j) ws[WS_ATTN + tid + j * 1024] = e[j] * inv;
}

// ---- kernel 5: context[d] = sum_t attn[t]*enc[t][d] (atomic over t-chunks) ----
__global__ __launch_bounds__(256) void k_context(const float* __restrict__ enc,
                                                 float* __restrict__ ws) {
  const int d = blockIdx.x * 256 + threadIdx.x;
  const int t0 = blockIdx.y * 256;
  const float* attn = ws + WS_ATTN;
  float s = 0.f;
  for (int t = t0; t < t0 + 256; ++t) s += attn[t] * enc[(size_t)t * D_ + d];
  atomicAdd(&ws[WS_X + d], s);
}

// ---- kernel 6: LSTM gates (wave per row) ----
__global__ __launch_bounds__(256) void k_gates(const float* __restrict__ Wih,
    const float* __restrict__ Whh, const float* __restrict__ bih,
    const float* __restrict__ bhh, const float* __restrict__ h0,
    float* __restrict__ ws) {
  const int wid = threadIdx.x >> 6, lane = threadIdx.x & 63;
  const int row = blockIdx.x * 4 + wid;
  float s = wave_dot4(Wih + (size_t)row * (D_ + IN_), ws + WS_X, (D_ + IN_) / 4, lane)
          + wave_dot4(Whh + (size_t)row * D_, h0, D_ / 4, lane);
  if (lane == 0) ws[WS_GATES + row] = s + bih[row] + bhh[row];
}

// ---- kernel 7: LSTM cell elementwise -> h_new, c_new ----
__global__ __launch_bounds__(256) void k_cell(const float* __restrict__ c0,
    float* __restrict__ ws, float* __restrict__ out) {
  const int d = blockIdx.x * 256 + threadIdx.x;
  const float* gt = ws + WS_GATES;
  const float gi = gt[d], gf = gt[D_ + d], gg = gt[2 * D_ + d], go = gt[3 * D_ + d];
  const float si = 1.f / (1.f + expf(-gi));
  const float sf = 1.f / (1.f + expf(-gf));
  const float so = 1.f / (1.f + expf(-go));
  const float cn = sf * c0[d] + si * tanhf(gg);
  const float hn = so * tanhf(cn);
  out[1 + 2 * D_ + d] = hn;
  out[1 + 3 * D_ + d] = cn;
  ws[WS_HN + d] = hn;
}

// ---- kernel 8: fc = lin_w @ h_new + lin_b ----
__global__ __launch_bounds__(256) void k_fc(const float* __restrict__ lw,
    const float* __restrict__ lb, float* __restrict__ ws) {
  const int wid = threadIdx.x >> 6, lane = threadIdx.x & 63;
  const int row = blockIdx.x * 4 + wid;
  float s = wave_dot4(lw + (size_t)row * D_, ws + WS_HN, D_ / 4, lane);
  if (lane == 0) ws[WS_FC + row] = s + lb[row];
}

// ---- kernel 9: l1 = lin1@fc+b, beta = softplus(lin2@fc+b) ----
__global__ __launch_bounds__(256) void k_l1beta(const float* __restrict__ l1w,
    const float* __restrict__ l1b, const float* __restrict__ l2w,
    const float* __restrict__ l2b, float* __restrict__ ws, float* __restrict__ out) {
  const int wid = threadIdx.x >> 6, lane = threadIdx.x & 63;
  const int row = blockIdx.x * 4 + wid;
  float a = wave_dot4(l1w + (size_t)row * D_, ws + WS_FC, D_ / 4, lane);
  float b = wave_dot4(l2w + (size_t)row * D_, ws + WS_FC, D_ / 4, lane);
  if (lane == 0) {
    ws[WS_L1 + row] = a + l1b[row];
    const float x = b + l2b[row];
    out[1 + row] = (x > 20.f) ? x : log1pf(expf(x));
  }
}

// ---- kernel 10: delta = softmax(l1), gamma = dense_w@l1 + dense_b ----
__global__ __launch_bounds__(256) void k_final(const float* __restrict__ dw,
    const float* __restrict__ db, float* __restrict__ ws, float* __restrict__ out) {
  __shared__ float sm[4];
  const int tid = threadIdx.x, lane = tid & 63, wid = tid >> 6;
  float v[8];
  #pragma unroll
  for (int j = 0; j < 8; ++j) v[j] = ws[WS_L1 + tid + j * 256];
  float mx = v[0];
  #pragma unroll
  for (int j = 1; j < 8; ++j) mx = fmaxf(mx, v[j]);
  #pragma unroll
  for (int m = 32; m >= 1; m >>= 1) mx = fmaxf(mx, __shfl_xor(mx, m, 64));
  if (lane == 0) sm[wid] = mx;
  __syncthreads();
  mx = fmaxf(fmaxf(sm[0], sm[1]), fmaxf(sm[2], sm[3]));
  __syncthreads();
  float e[8], ls = 0.f;
  #pragma unroll
  for (int j = 0; j < 8; ++j) { e[j] = expf(v[j] - mx); ls += e[j]; }
  #pragma unroll
  for (int m = 32; m >= 1; m >>= 1) ls += __shfl_xor(ls, m, 64);
  if (lane == 0) sm[wid] = ls;
  __syncthreads();
  ls = sm[0] + sm[1] + sm[2] + sm[3];
  __syncthreads();
  const float inv = 1.f / ls;
  float gp = 0.f;
  #pragma unroll
  for (int j = 0; j < 8; ++j) {
    out[1 + D_ + tid + j * 256] = e[j] * inv;
    gp += v[j] * dw[tid + j * 256];
  }
  #pragma unroll
  for (int m = 32; m >= 1; m >>= 1) gp += __shfl_xor(gp, m, 64);
  if (lane == 0) sm[wid] = gp;
  __syncthreads();
  if (tid == 0) out[0] = sm[0] + sm[1] + sm[2] + sm[3] + db[0];
}

extern "C" void kernel_launch(void* const* d_in, const int* in_sizes, int n_in,
                              void* d_out, int out_size, void* d_ws, size_t ws_size,
                              hipStream_t stream) {
  (void)in_sizes; (void)n_in; (void)out_size; (void)ws_size;
  const float* data   = (const float*)d_in[0];
  const float* h0     = (const float*)d_in[1];
  const float* c0     = (const float*)d_in[2];
  const float* enc    = (const float*)d_in[3];
  const float* pi     = (const float*)d_in[4];
  const float* Ww     = (const float*)d_in[5];
  const float* Uw     = (const float*)d_in[6];
  const float* Vw     = (const float*)d_in[7];
  const float* lin_w  = (const float*)d_in[8];
  const float* lin_b  = (const float*)d_in[9];
  const float* lin1_w = (const float*)d_in[10];
  const float* lin1_b = (const float*)d_in[11];
  const float* lin2_w = (const float*)d_in[12];
  const float* lin2_b = (const float*)d_in[13];
  const float* dw     = (const float*)d_in[14];
  const float* db     = (const float*)d_in[15];
  const float* Wih    = (const float*)d_in[16];
  const float* Whh    = (const float*)d_in[17];
  const float* bih    = (const float*)d_in[18];
  const float* bhh    = (const float*)d_in[19];
  const int*   ip     = (const int*)d_in[20];
  float* ws  = (float*)d_ws;
  float* out = (float*)d_out;

  // zero the context accumulator (atomicAdd target) every launch
  hipMemsetAsync(ws + WS_X, 0, D_ * sizeof(float), stream);
  k_prep<<<512, 256, 0, stream>>>(Ww, h0, pi, data, ip, ws);
  k_gemm_score<<<dim3(T_ / 128, D_ / 128), 256, 0, stream>>>(enc, Uw, Vw, ws);
  k_score<<<T_ / 256, 256, 0, stream>>>(ip, ws);
  k_attn<<<1, 1024, 0, stream>>>(ws);
  k_context<<<dim3(D_ / 256, T_ / 256), 256, 0, stream>>>(enc, ws);
  k_gates<<<G4_ / 4, 256, 0, stream>>>(Wih, Whh, bih, bhh, h0, ws);
  k_cell<<<D_ / 256, 256, 0, stream>>>(c0, ws, out);
  k_fc<<<D_ / 4, 256, 0, stream>>>(lin_w, lin_b, ws);
  k_l1beta<<<D_ / 4, 256, 0, stream>>>(lin1_w, lin1_b, lin2_w, lin2_b, ws, out);
  k_final<<<1, 256, 0, stream>>>(dw, db, ws, out);
}

// Round 2
// 136.893 us; speedup vs baseline: 1.4387x; 1.4387x over previous
//
#include <hip/hip_runtime.h>
#include <hip/hip_bf16.h>

#define D_  2048
#define IN_ 512
#define T_  4096
#define G4_ 8192

typedef __attribute__((ext_vector_type(4))) float f32x4;
typedef __attribute__((ext_vector_type(8))) short s16x8;

// ws layout (float offsets)
#define WS_PROD    0                        // T_
#define WS_Q       (T_)                     // D_
#define WS_X       (T_ + D_)                // D_+IN_ : [context | data]
#define WS_PARTIAL (WS_X + D_ + IN_)        // T_*16
#define WS_SCORE   (WS_PARTIAL + T_*16)     // T_
#define WS_ATTN    (WS_SCORE + T_)          // T_
#define WS_GATES   (WS_ATTN + T_)           // G4_
#define WS_G2      (WS_GATES + G4_)         // G4_  (Whh@h0 partial)
#define WS_FC      (WS_G2 + G4_)            // D_
#define WS_L1      (WS_FC + D_)             // D_
#define WS_HN      (WS_L1 + D_)             // D_

__device__ inline short bfbits(__hip_bfloat16 h) {
  union { __hip_bfloat16 b; short s; } u; u.b = h; return u.s;
}

// full-row dot by one wave; returns sum in all lanes
__device__ inline float wave_dot4(const float* __restrict__ w,
                                  const float* __restrict__ x, int n4, int lane) {
  float s = 0.f;
  const f32x4* w4 = (const f32x4*)w;
  const f32x4* x4 = (const f32x4*)x;
  for (int c = lane; c < n4; c += 64) {
    f32x4 a = w4[c], b = x4[c];
    s += a[0]*b[0] + a[1]*b[1] + a[2]*b[2] + a[3]*b[3];
  }
  #pragma unroll
  for (int m = 32; m >= 1; m >>= 1) s += __shfl_xor(s, m, 64);
  return s;
}

// ---- kernel 1: prod[t], q = W_w @ h0, copy data into x tail ----
__global__ __launch_bounds__(256) void k_prep(const float* __restrict__ Ww,
    const float* __restrict__ h0, const float* __restrict__ pi,
    const float* __restrict__ data, const int* __restrict__ ip,
    float* __restrict__ ws) {
  const int tid = threadIdx.x, bid = blockIdx.x;
  const int gidx = bid * 256 + tid;
  const int op = ip[0] + 1;
  if (gidx < T_) {
    float p = 0.f;
    if (gidx >= op - 1) {
      int idx = op + T_ - gidx - 2;
      idx = idx < 0 ? 0 : (idx > T_ - 1 ? T_ - 1 : idx);
      p = pi[idx];
    }
    ws[WS_PROD + gidx] = p;
  }
  if (gidx < IN_) ws[WS_X + D_ + gidx] = data[gidx];
  const int wid = tid >> 6, lane = tid & 63;
  const int row = bid * 4 + wid;
  if (row < D_) {
    float s = wave_dot4(Ww + (size_t)row * D_, h0, D_ / 4, lane);
    if (lane == 0) ws[WS_Q + row] = s;
  }
}

// ---- kernel 2: bf16 MFMA GEMM (1-term) + tanh/V epilogue + Whh@h0 tail ----
__global__ __launch_bounds__(512, 4) void k_gemm_score(
    const float* __restrict__ enc, const float* __restrict__ Uw,
    const float* __restrict__ Vw, const float* __restrict__ h0,
    const float* __restrict__ Whh, float* __restrict__ ws) {
  __shared__ __align__(16) short sbuf[2 * 128 * 40];
  short* Ah = sbuf;
  short* Bh = sbuf + 128 * 40;
  const int tid = threadIdx.x;
  const int lane = tid & 63, wid = tid >> 6;
  const int wr = wid >> 2, wc = wid & 3;       // 2 x 4 wave grid
  const int g = lane >> 4, lr = lane & 15;
  const int mb = blockIdx.x, nb = blockIdx.y;

  f32x4 acc[4][2];
  #pragma unroll
  for (int m = 0; m < 4; ++m)
    #pragma unroll
    for (int n = 0; n < 2; ++n) acc[m][n] = (f32x4){0.f, 0.f, 0.f, 0.f};

  const int srow = tid >> 2;                   // 0..127
  const int scol = (tid & 3) * 8;              // 0,8,16,24
  const float* pa0 = enc + (size_t)(mb * 128 + srow) * D_ + scol;
  const float* pb0 = Uw  + (size_t)(nb * 128 + srow) * D_ + scol;
  const int sidx = srow * 40 + scol;

  // prefetch ks=0
  f32x4 an0 = *(const f32x4*)(pa0);
  f32x4 an1 = *(const f32x4*)(pa0 + 4);
  f32x4 bn0 = *(const f32x4*)(pb0);
  f32x4 bn1 = *(const f32x4*)(pb0 + 4);

  for (int ks = 0; ks < 64; ++ks) {
    f32x4 a0 = an0, a1 = an1, b0 = bn0, b1 = bn1;
    if (ks < 63) {
      an0 = *(const f32x4*)(pa0 + (ks + 1) * 32);
      an1 = *(const f32x4*)(pa0 + (ks + 1) * 32 + 4);
      bn0 = *(const f32x4*)(pb0 + (ks + 1) * 32);
      bn1 = *(const f32x4*)(pb0 + (ks + 1) * 32 + 4);
    }
    __syncthreads();   // previous iteration's LDS reads done
    __align__(16) short ah[8], bh[8];
    #pragma unroll
    for (int e = 0; e < 4; ++e) {
      ah[e]     = bfbits(__float2bfloat16(a0[e]));
      ah[4 + e] = bfbits(__float2bfloat16(a1[e]));
      bh[e]     = bfbits(__float2bfloat16(b0[e]));
      bh[4 + e] = bfbits(__float2bfloat16(b1[e]));
    }
    *(s16x8*)&Ah[sidx] = *(s16x8*)&ah[0];
    *(s16x8*)&Bh[sidx] = *(s16x8*)&bh[0];
    __syncthreads();

    s16x8 af[4], bf[2];
    #pragma unroll
    for (int m = 0; m < 4; ++m)
      af[m] = *(const s16x8*)&Ah[(wr * 64 + m * 16 + lr) * 40 + g * 8];
    #pragma unroll
    for (int n = 0; n < 2; ++n)
      bf[n] = *(const s16x8*)&Bh[(wc * 32 + n * 16 + lr) * 40 + g * 8];
    #pragma unroll
    for (int m = 0; m < 4; ++m)
      #pragma unroll
      for (int n = 0; n < 2; ++n)
        acc[m][n] = __builtin_amdgcn_mfma_f32_16x16x32_bf16(af[m], bf[n], acc[m][n], 0, 0, 0);
  }

  // epilogue: per-row partial of score = sum_d V[d]*tanh(q[d] + prod[t]*C[t][d])
  const float* q    = ws + WS_Q;
  const float* prod = ws + WS_PROD;
  float Vv[2], qv[2];
  #pragma unroll
  for (int n = 0; n < 2; ++n) {
    const int d = nb * 128 + wc * 32 + n * 16 + lr;
    Vv[n] = Vw[d]; qv[n] = q[d];
  }
  __syncthreads();
  float* red = (float*)sbuf;   // 128 x 4 floats
  #pragma unroll
  for (int m = 0; m < 4; ++m) {
    #pragma unroll
    for (int r = 0; r < 4; ++r) {
      const int t_loc = wr * 64 + m * 16 + g * 4 + r;
      const float p = prod[mb * 128 + t_loc];
      float s = Vv[0] * tanhf(qv[0] + p * acc[m][0][r])
              + Vv[1] * tanhf(qv[1] + p * acc[m][1][r]);
      s += __shfl_xor(s, 1, 64);
      s += __shfl_xor(s, 2, 64);
      s += __shfl_xor(s, 4, 64);
      s += __shfl_xor(s, 8, 64);
      if (lr == 0) red[t_loc * 4 + wc] = s;
    }
  }
  __syncthreads();
  if (tid < 128) {
    const float s = red[tid * 4] + red[tid * 4 + 1] + red[tid * 4 + 2] + red[tid * 4 + 3];
    ws[WS_PARTIAL + (size_t)(mb * 128 + tid) * 16 + nb] = s;
  }

  // Whh @ h0 tail: 16 rows per block, 2 per wave (overlaps other blocks' GEMM)
  const int flat = blockIdx.y * gridDim.x + blockIdx.x;   // 0..511
  const int rbase = flat * 16 + wid * 2;
  #pragma unroll
  for (int rr = 0; rr < 2; ++rr) {
    const int row = rbase + rr;
    float s = wave_dot4(Whh + (size_t)row * D_, h0, D_ / 4, lane);
    if (lane == 0) ws[WS_G2 + row] = s;
  }
}

// ---- kernel 3: reduce partials -> masked score ----
__global__ __launch_bounds__(256) void k_score(const int* __restrict__ ip,
                                               float* __restrict__ ws) {
  const int t = blockIdx.x * 256 + threadIdx.x;
  const int op = ip[0] + 1;
  const float* p = ws + WS_PARTIAL + (size_t)t * 16;
  float s = 0.f;
  #pragma unroll
  for (int c = 0; c < 16; ++c) s += p[c];
  ws[WS_SCORE + t] = (t < op) ? 0.f : s;
}

// ---- kernel 4: softmax over T scores (single block) ----
__global__ __launch_bounds__(1024) void k_attn(float* __restrict__ ws) {
  __shared__ float sm[16];
  const int tid = threadIdx.x, lane = tid & 63, wid = tid >> 6;
  float v[4];
  #pragma unroll
  for (int j = 0; j < 4; ++j) v[j] = ws[WS_SCORE + tid + j * 1024];
  float mx = fmaxf(fmaxf(v[0], v[1]), fmaxf(v[2], v[3]));
  #pragma unroll
  for (int m = 32; m >= 1; m >>= 1) mx = fmaxf(mx, __shfl_xor(mx, m, 64));
  if (lane == 0) sm[wid] = mx;
  __syncthreads();
  if (tid == 0) {
    float m2 = sm[0];
    for (int w = 1; w < 16; ++w) m2 = fmaxf(m2, sm[w]);
    sm[0] = m2;
  }
  __syncthreads();
  mx = sm[0];
  __syncthreads();
  float e[4], ls = 0.f;
  #pragma unroll
  for (int j = 0; j < 4; ++j) { e[j] = expf(v[j] - mx); ls += e[j]; }
  #pragma unroll
  for (int m = 32; m >= 1; m >>= 1) ls += __shfl_xor(ls, m, 64);
  if (lane == 0) sm[wid] = ls;
  __syncthreads();
  if (tid == 0) {
    float s2 = 0.f;
    for (int w = 0; w < 16; ++w) s2 += sm[w];
    sm[0] = s2;
  }
  __syncthreads();
  const float inv = 1.f / sm[0];
  #pragma unroll
  for (int j = 0; j < 4; ++j) ws[WS_ATTN + tid + j * 1024] = e[j] * inv;
}

// ---- kernel 5: context[d] = sum_t attn[t]*enc[t][d] ----
__global__ __launch_bounds__(256) void k_context(const float* __restrict__ enc,
                                                 float* __restrict__ ws) {
  const int d = blockIdx.x * 256 + threadIdx.x;
  const int t0 = blockIdx.y * 256;
  const float* attn = ws + WS_ATTN;
  float s = 0.f;
  for (int t = t0; t < t0 + 256; ++t) s += attn[t] * enc[(size_t)t * D_ + d];
  atomicAdd(&ws[WS_X + d], s);
}

// ---- kernel 6: LSTM gates: Wih@x + precomputed Whh@h0 partial ----
__global__ __launch_bounds__(256) void k_gates(const float* __restrict__ Wih,
    const float* __restrict__ bih, const float* __restrict__ bhh,
    float* __restrict__ ws) {
  const int wid = threadIdx.x >> 6, lane = threadIdx.x & 63;
  const int row = blockIdx.x * 4 + wid;
  float s = wave_dot4(Wih + (size_t)row * (D_ + IN_), ws + WS_X, (D_ + IN_) / 4, lane);
  if (lane == 0) ws[WS_GATES + row] = s + ws[WS_G2 + row] + bih[row] + bhh[row];
}

// ---- kernel 7: LSTM cell elementwise -> h_new, c_new ----
__global__ __launch_bounds__(256) void k_cell(const float* __restrict__ c0,
    float* __restrict__ ws, float* __restrict__ out) {
  const int d = blockIdx.x * 256 + threadIdx.x;
  const float* gt = ws + WS_GATES;
  const float gi = gt[d], gf = gt[D_ + d], gg = gt[2 * D_ + d], go = gt[3 * D_ + d];
  const float si = 1.f / (1.f + expf(-gi));
  const float sf = 1.f / (1.f + expf(-gf));
  const float so = 1.f / (1.f + expf(-go));
  const float cn = sf * c0[d] + si * tanhf(gg);
  const float hn = so * tanhf(cn);
  out[1 + 2 * D_ + d] = hn;
  out[1 + 3 * D_ + d] = cn;
  ws[WS_HN + d] = hn;
}

// ---- kernel 8: fc = lin_w @ h_new + lin_b ----
__global__ __launch_bounds__(256) void k_fc(const float* __restrict__ lw,
    const float* __restrict__ lb, float* __restrict__ ws) {
  const int wid = threadIdx.x >> 6, lane = threadIdx.x & 63;
  const int row = blockIdx.x * 4 + wid;
  float s = wave_dot4(lw + (size_t)row * D_, ws + WS_HN, D_ / 4, lane);
  if (lane == 0) ws[WS_FC + row] = s + lb[row];
}

// ---- kernel 9: l1 = lin1@fc+b, beta = softplus(lin2@fc+b) ----
__global__ __launch_bounds__(256) void k_l1beta(const float* __restrict__ l1w,
    const float* __restrict__ l1b, const float* __restrict__ l2w,
    const float* __restrict__ l2b, float* __restrict__ ws, float* __restrict__ out) {
  const int wid = threadIdx.x >> 6, lane = threadIdx.x & 63;
  const int row = blockIdx.x * 4 + wid;
  float a = wave_dot4(l1w + (size_t)row * D_, ws + WS_FC, D_ / 4, lane);
  float b = wave_dot4(l2w + (size_t)row * D_, ws + WS_FC, D_ / 4, lane);
  if (lane == 0) {
    ws[WS_L1 + row] = a + l1b[row];
    const float x = b + l2b[row];
    out[1 + row] = (x > 20.f) ? x : log1pf(expf(x));
  }
}

// ---- kernel 10: delta = softmax(l1), gamma = dense_w@l1 + dense_b ----
__global__ __launch_bounds__(256) void k_final(const float* __restrict__ dw,
    const float* __restrict__ db, float* __restrict__ ws, float* __restrict__ out) {
  __shared__ float sm[4];
  const int tid = threadIdx.x, lane = tid & 63, wid = tid >> 6;
  float v[8];
  #pragma unroll
  for (int j = 0; j < 8; ++j) v[j] = ws[WS_L1 + tid + j * 256];
  float mx = v[0];
  #pragma unroll
  for (int j = 1; j < 8; ++j) mx = fmaxf(mx, v[j]);
  #pragma unroll
  for (int m = 32; m >= 1; m >>= 1) mx = fmaxf(mx, __shfl_xor(mx, m, 64));
  if (lane == 0) sm[wid] = mx;
  __syncthreads();
  mx = fmaxf(fmaxf(sm[0], sm[1]), fmaxf(sm[2], sm[3]));
  __syncthreads();
  float e[8], ls = 0.f;
  #pragma unroll
  for (int j = 0; j < 8; ++j) { e[j] = expf(v[j] - mx); ls += e[j]; }
  #pragma unroll
  for (int m = 32; m >= 1; m >>= 1) ls += __shfl_xor(ls, m, 64);
  if (lane == 0) sm[wid] = ls;
  __syncthreads();
  ls = sm[0] + sm[1] + sm[2] + sm[3];
  __syncthreads();
  const float inv = 1.f / ls;
  float gp = 0.f;
  #pragma unroll
  for (int j = 0; j < 8; ++j) {
    out[1 + D_ + tid + j * 256] = e[j] * inv;
    gp += v[j] * dw[tid + j * 256];
  }
  #pragma unroll
  for (int m = 32; m >= 1; m >>= 1) gp += __shfl_xor(gp, m, 64);
  if (lane == 0) sm[wid] = gp;
  __syncthreads();
  if (tid == 0) out[0] = sm[0] + sm[1] + sm[2] + sm[3] + db[0];
}

extern "C" void kernel_launch(void* const* d_in, const int* in_sizes, int n_in,
                              void* d_out, int out_size, void* d_ws, size_t ws_size,
                              hipStream_t stream) {
  (void)in_sizes; (void)n_in; (void)out_size; (void)ws_size;
  const float* data   = (const float*)d_in[0];
  const float* h0     = (const float*)d_in[1];
  const float* c0     = (const float*)d_in[2];
  const float* enc    = (const float*)d_in[3];
  const float* pi     = (const float*)d_in[4];
  const float* Ww     = (const float*)d_in[5];
  const float* Uw     = (const float*)d_in[6];
  const float* Vw     = (const float*)d_in[7];
  const float* lin_w  = (const float*)d_in[8];
  const float* lin_b  = (const float*)d_in[9];
  const float* lin1_w = (const float*)d_in[10];
  const float* lin1_b = (const float*)d_in[11];
  const float* lin2_w = (const float*)d_in[12];
  const float* lin2_b = (const float*)d_in[13];
  const float* dw     = (const float*)d_in[14];
  const float* db     = (const float*)d_in[15];
  const float* Wih    = (const float*)d_in[16];
  const float* Whh    = (const float*)d_in[17];
  const float* bih    = (const float*)d_in[18];
  const float* bhh    = (const float*)d_in[19];
  const int*   ip     = (const int*)d_in[20];
  float* ws  = (float*)d_ws;
  float* out = (float*)d_out;

  // zero the context accumulator (atomicAdd target) every launch
  hipMemsetAsync(ws + WS_X, 0, D_ * sizeof(float), stream);
  k_prep<<<512, 256, 0, stream>>>(Ww, h0, pi, data, ip, ws);
  k_gemm_score<<<dim3(T_ / 128, D_ / 128), 512, 0, stream>>>(enc, Uw, Vw, h0, Whh, ws);
  k_score<<<T_ / 256, 256, 0, stream>>>(ip, ws);
  k_attn<<<1, 1024, 0, stream>>>(ws);
  k_context<<<dim3(D_ / 256, T_ / 256), 256, 0, stream>>>(enc, ws);
  k_gates<<<G4_ / 4, 256, 0, stream>>>(Wih, bih, bhh, ws);
  k_cell<<<D_ / 256, 256, 0, stream>>>(c0, ws, out);
  k_fc<<<D_ / 4, 256, 0, stream>>>(lin_w, lin_b, ws);
  k_l1beta<<<D_ / 4, 256, 0, stream>>>(lin1_w, lin1_b, lin2_w, lin2_b, ws, out);
  k_final<<<1, 256, 0, stream>>>(dw, db, ws, out);
}